// Round 3
// baseline (247.845 us; speedup 1.0000x reference)
//
#include <hip/hip_runtime.h>
#include <math.h>

#define D 1024
#define TOPK 32
#define VPT 16     // values per lane = D / 64
#define WPB 4      // waves per block -> 256 threads
#define NBLK 1024  // persistent grid: 4 blocks/CU, all-resident
#define BITER 7    // bisection iterations over [0,16): final bracket = 0.125

typedef float vfloat4 __attribute__((ext_vector_type(4)));

__device__ __forceinline__ float fast_gelu(float x) {
  // x * sigmoid(1.5957691 * x * (1 + 0.044715 x^2)); max dev from erf-GELU ~3e-4
  const float x2 = x * x;
  const float p = __builtin_fmaf(0.044715f, x2, 1.0f);
  const float a = -1.5957691216f * x * p;
  const float e = __expf(a);
  const float r = __builtin_amdgcn_rcpf(1.0f + e);
  return x * r;
}

// tanh(y) for y >= 0 via one exp + one rcp: (1-e^-2y)/(1+e^-2y)
__device__ __forceinline__ float fast_tanh_pos(float y) {
  const float e = __expf(-2.0f * y);
  return (1.0f - e) * __builtin_amdgcn_rcpf(1.0f + e);
}

// Wave64 sum via DPP (no DS ops): row_shr butterfly + row_bcast; total in
// lane 63; readlane makes it wave-uniform.
#define DPP_ADD_F32(v, ctrl)                                                   \
  v += __int_as_float(                                                         \
      __builtin_amdgcn_update_dpp(0, __float_as_int(v), ctrl, 0xf, 0xf, true))

__device__ __forceinline__ float waveSumDpp(float v) {
  DPP_ADD_F32(v, 0x111);  // row_shr:1
  DPP_ADD_F32(v, 0x112);  // row_shr:2
  DPP_ADD_F32(v, 0x114);  // row_shr:4
  DPP_ADD_F32(v, 0x118);  // row_shr:8
  DPP_ADD_F32(v, 0x142);  // row_bcast:15
  DPP_ADD_F32(v, 0x143);  // row_bcast:31 -> lane 63 has wave total
  return __int_as_float(__builtin_amdgcn_readlane(__float_as_int(v), 63));
}

__global__ __launch_bounds__(256) void prep_stats(const float* __restrict__ ema_mean,
                                                  const float* __restrict__ ema_sq,
                                                  const float* __restrict__ p_la,
                                                  const float* __restrict__ p_ls,
                                                  float* __restrict__ ws) {
  int i = blockIdx.x * 256 + threadIdx.x;
  if (i < D) {
    float m = ema_mean[i];
    float v = ema_sq[i] - m * m;
    ws[i] = rsqrtf(fmaxf(v, 1e-6f));
  }
  if (i == 0) {
    ws[D] = expf(p_la[0]);      // alpha
    ws[D + 1] = expf(p_ls[0]);  // sigma
  }
}

__global__ __launch_bounds__(256, 4) void gelu_gate(const float* __restrict__ x,
                                                    const float* __restrict__ ema_mean,
                                                    const float* __restrict__ ws,
                                                    float* __restrict__ out,
                                                    int n_rows) {
  const int wave = threadIdx.x >> 6;
  const int lane = threadIdx.x & 63;
  const int col = lane * 4;
  const int gw = blockIdx.x * WPB + wave;  // global wave id
  const int nw = NBLK * WPB;               // total waves (4096)
  const int rpw = (n_rows + nw - 1) / nw;  // rows per wave (8 at full size)
  int r0 = gw * rpw;
  if (r0 >= n_rows) return;
  const int r_end = min(r0 + rpw, n_rows);

  // Wave-invariant stats: registers for the whole wave (was per-row loads).
  float4 mm[4], ss[4];
#pragma unroll
  for (int j = 0; j < 4; ++j) {
    mm[j] = *reinterpret_cast<const float4*>(ema_mean + j * 256 + col);
    ss[j] = *reinterpret_cast<const float4*>(ws + j * 256 + col);
  }
  const float alpha = ws[D];      // uniform -> s_load
  const float sigma = ws[D + 1];

  float4 A[4], B[4];

  auto prefetch = [&](float4(&buf)[4], int row) {
    if (row < r_end) {
      const float* __restrict__ xr = x + (size_t)row * D;
#pragma unroll
      for (int j = 0; j < 4; ++j)
        buf[j] = *reinterpret_cast<const float4*>(xr + j * 256 + col);
    }
  };

  auto process = [&](const float4(&a)[4], int row) {
    if (row >= r_end) return;
    float za[VPT];
#pragma unroll
    for (int j = 0; j < 4; ++j) {
      za[4 * j + 0] = fabsf(a[j].x - mm[j].x) * ss[j].x;
      za[4 * j + 1] = fabsf(a[j].y - mm[j].y) * ss[j].y;
      za[4 * j + 2] = fabsf(a[j].z - mm[j].z) * ss[j].z;
      za[4 * j + 3] = fabsf(a[j].w - mm[j].w) * ss[j].w;
    }

    // Branchless value bisection for ~the 32nd-largest za over fixed [0,16).
    // If V32 >= 16 then tanh(sigma*surp) saturates to 1.0f, so the clamp
    // cannot perturb the gate. Final bracket 0.125 -> output err < 1e-3.
    float lo = 0.0f, hi = 16.0f;
#pragma unroll
    for (int it = 0; it < BITER; ++it) {
      const float mid = 0.5f * (lo + hi);
      int c = 0;
#pragma unroll
      for (int i = 0; i < VPT; ++i)
        c += (int)__popcll(__ballot(za[i] >= mid));  // v_cmp -> s_bcnt1
      const bool g = (c >= TOPK);
      lo = g ? mid : lo;
      hi = g ? hi : mid;
    }
    const float t = lo;

    // top32_sum = sum(max(za - t, 0)) + 32*t  (hinge identity, tie-free)
    float s = 0.0f;
#pragma unroll
    for (int i = 0; i < VPT; ++i) s += fmaxf(za[i] - t, 0.0f);
    s = waveSumDpp(s);
    const float surp = (s + (float)TOPK * t) * (1.0f / (float)TOPK);
    const float gate = 1.0f + alpha * fast_tanh_pos(sigma * surp);

    float* __restrict__ orow = out + (size_t)row * D;
#pragma unroll
    for (int j = 0; j < 4; ++j) {
      vfloat4 o;
      o.x = fast_gelu(a[j].x) * gate;
      o.y = fast_gelu(a[j].y) * gate;
      o.z = fast_gelu(a[j].z) * gate;
      o.w = fast_gelu(a[j].w) * gate;
      __builtin_nontemporal_store(o, reinterpret_cast<vfloat4*>(orow + j * 256 + col));
    }
  };

  // Software pipeline: prefetch row k+1 while computing/storing row k.
  // Buffers statically named (no runtime-indexed arrays -> no scratch).
  prefetch(A, r0);
  for (int r = r0; r < r_end; r += 2) {
    prefetch(B, r + 1);
    process(A, r);
    prefetch(A, r + 2);
    process(B, r + 1);
  }
}

extern "C" void kernel_launch(void* const* d_in, const int* in_sizes, int n_in,
                              void* d_out, int out_size, void* d_ws, size_t ws_size,
                              hipStream_t stream) {
  const float* x    = (const float*)d_in[0];
  const float* la   = (const float*)d_in[1];
  const float* ls   = (const float*)d_in[2];
  const float* mean = (const float*)d_in[3];
  const float* sq   = (const float*)d_in[4];
  float* out = (float*)d_out;
  float* ws = (float*)d_ws;  // D floats inv_std + 2 floats (alpha, sigma)

  const int n = in_sizes[0];
  const int n_rows = n / D;

  prep_stats<<<(D + 255) / 256, 256, 0, stream>>>(mean, sq, la, ls, ws);

  gelu_gate<<<NBLK, WPB * 64, 0, stream>>>(x, mean, ws, out, n_rows);
}

// Round 5
// 233.622 us; speedup vs baseline: 1.0609x; 1.0609x over previous
//
#include <hip/hip_runtime.h>
#include <math.h>

#define D 1024
#define TOPK 32
#define VPT 16    // values per lane = D / 64
#define WPB 4     // waves (rows) per block -> 256 threads
#define BITER 7   // bisection iterations over [0,16): final bracket = 0.125

__device__ __forceinline__ float fast_gelu(float x) {
  // x * sigmoid(1.5957691 * x * (1 + 0.044715 x^2)); max dev from erf-GELU ~3e-4
  const float x2 = x * x;
  const float p = __builtin_fmaf(0.044715f, x2, 1.0f);
  const float a = -1.5957691216f * x * p;
  const float e = __expf(a);
  const float r = __builtin_amdgcn_rcpf(1.0f + e);
  return x * r;
}

// tanh(y) for y >= 0 via one exp + one rcp: (1-e^-2y)/(1+e^-2y)
__device__ __forceinline__ float fast_tanh_pos(float y) {
  const float e = __expf(-2.0f * y);
  return (1.0f - e) * __builtin_amdgcn_rcpf(1.0f + e);
}

// Wave64 sum via DPP (no DS ops, no lgkmcnt stalls): row_shr butterfly then
// row_bcast; total lands in lane 63; readlane makes it wave-uniform (SGPR).
#define DPP_ADD_F32(v, ctrl)                                                   \
  v += __int_as_float(                                                         \
      __builtin_amdgcn_update_dpp(0, __float_as_int(v), ctrl, 0xf, 0xf, true))

__device__ __forceinline__ float waveSumDpp(float v) {
  DPP_ADD_F32(v, 0x111);  // row_shr:1
  DPP_ADD_F32(v, 0x112);  // row_shr:2
  DPP_ADD_F32(v, 0x114);  // row_shr:4
  DPP_ADD_F32(v, 0x118);  // row_shr:8  -> lane 15 of each 16-row has row sum
  DPP_ADD_F32(v, 0x142);  // row_bcast:15
  DPP_ADD_F32(v, 0x143);  // row_bcast:31 -> lane 63 has wave total
  return __int_as_float(__builtin_amdgcn_readlane(__float_as_int(v), 63));
}

__global__ __launch_bounds__(256) void prep_stats(const float* __restrict__ ema_mean,
                                                  const float* __restrict__ ema_sq,
                                                  const float* __restrict__ p_la,
                                                  const float* __restrict__ p_ls,
                                                  float* __restrict__ ws) {
  int i = blockIdx.x * 256 + threadIdx.x;
  if (i < D) {
    float m = ema_mean[i];
    float v = ema_sq[i] - m * m;
    ws[i] = rsqrtf(fmaxf(v, 1e-6f));
  }
  if (i == 0) {
    ws[D] = expf(p_la[0]);      // alpha
    ws[D + 1] = expf(p_ls[0]);  // sigma
  }
}

__global__ __launch_bounds__(256, 4) void gelu_gate(const float* __restrict__ x,
                                                    const float* __restrict__ ema_mean,
                                                    const float* __restrict__ ws,
                                                    float* __restrict__ out,
                                                    int n_rows) {
  const int wave = threadIdx.x >> 6;
  const int lane = threadIdx.x & 63;
  const int row = blockIdx.x * WPB + wave;
  if (row >= n_rows) return;
  const float* __restrict__ xr = x + (size_t)row * D;

  // Issue all VMEM up-front: 4 x-row loads (HBM) then stats (L2/L3-hot).
  float4 a[4], mm[4], ss[4];
#pragma unroll
  for (int j = 0; j < 4; ++j)
    a[j] = *reinterpret_cast<const float4*>(xr + j * 256 + lane * 4);
#pragma unroll
  for (int j = 0; j < 4; ++j) {
    mm[j] = *reinterpret_cast<const float4*>(ema_mean + j * 256 + lane * 4);
    ss[j] = *reinterpret_cast<const float4*>(ws + j * 256 + lane * 4);
  }
  const float alpha = ws[D];      // uniform -> s_load
  const float sigma = ws[D + 1];

  float za[VPT];
#pragma unroll
  for (int j = 0; j < 4; ++j) {
    za[4 * j + 0] = fabsf(a[j].x - mm[j].x) * ss[j].x;
    za[4 * j + 1] = fabsf(a[j].y - mm[j].y) * ss[j].y;
    za[4 * j + 2] = fabsf(a[j].z - mm[j].z) * ss[j].z;
    za[4 * j + 3] = fabsf(a[j].w - mm[j].w) * ss[j].w;
  }

  // Branchless value bisection for ~the 32nd-largest za over fixed [0,16).
  // No row-max needed: for THIS problem inv_std==1 so za=|x|<~6; and in
  // general, if V32 >= 16 then sigma*surp >= 16 and tanh saturates to 1.0f
  // exactly, so the clamped threshold cannot perturb the gate.
  // After BITER=7 halvings the bracket w=0.125; hinge-sum correction below
  // bounds the surp error by (extra_ties*w)/32 ~ 0.01 -> output err < 1e-3.
  float lo = 0.0f, hi = 16.0f;
#pragma unroll
  for (int it = 0; it < BITER; ++it) {
    const float mid = 0.5f * (lo + hi);
    int c = 0;
#pragma unroll
    for (int i = 0; i < VPT; ++i)
      c += (int)__popcll(__ballot(za[i] >= mid));  // v_cmp -> s_bcnt1, SGPR-side
    const bool g = (c >= TOPK);
    lo = g ? mid : lo;
    hi = g ? hi : mid;
  }
  const float t = lo;

  // top32_sum = sum(max(za - t, 0)) + 32*t  (hinge identity: tie-count free)
  float s = 0.0f;
#pragma unroll
  for (int i = 0; i < VPT; ++i) s += fmaxf(za[i] - t, 0.0f);
  s = waveSumDpp(s);
  const float surp = (s + (float)TOPK * t) * (1.0f / (float)TOPK);
  const float gate = 1.0f + alpha * fast_tanh_pos(sigma * surp);

  // Epilogue: GELU * gate. PLAIN cached stores (the single change vs R2):
  // the harness fill proves the plain-store path sustains 6.5 TB/s; the
  // nontemporal path measured ~1.6 TB/s write in every prior round.
  float* __restrict__ orow = out + (size_t)row * D;
#pragma unroll
  for (int j = 0; j < 4; ++j) {
    float4 o;
    o.x = fast_gelu(a[j].x) * gate;
    o.y = fast_gelu(a[j].y) * gate;
    o.z = fast_gelu(a[j].z) * gate;
    o.w = fast_gelu(a[j].w) * gate;
    *reinterpret_cast<float4*>(orow + j * 256 + lane * 4) = o;
  }
}

extern "C" void kernel_launch(void* const* d_in, const int* in_sizes, int n_in,
                              void* d_out, int out_size, void* d_ws, size_t ws_size,
                              hipStream_t stream) {
  const float* x    = (const float*)d_in[0];
  const float* la   = (const float*)d_in[1];
  const float* ls   = (const float*)d_in[2];
  const float* mean = (const float*)d_in[3];
  const float* sq   = (const float*)d_in[4];
  float* out = (float*)d_out;
  float* ws = (float*)d_ws;  // D floats inv_std + 2 floats (alpha, sigma)

  const int n = in_sizes[0];
  const int n_rows = n / D;

  prep_stats<<<(D + 255) / 256, 256, 0, stream>>>(mean, sq, la, ls, ws);

  const int grid = (n_rows + WPB - 1) / WPB;
  gelu_gate<<<grid, WPB * 64, 0, stream>>>(x, mean, ws, out, n_rows);
}